// Round 2
// baseline (414.494 us; speedup 1.0000x reference)
//
#include <hip/hip_runtime.h>
#include <stdint.h>

typedef short v8s __attribute__((ext_vector_type(8)));
typedef float f4 __attribute__((ext_vector_type(4)));
typedef unsigned short u16;
typedef unsigned int u32;

#define CUT1 19997
#define CUT2 39997
#define CUT3 199997
#define NROWS 1024
#define LDP 1360   // packed proj cols: 1024 + 256 + 64 + 16

#define NG_HEAD 157
#define NG_T1 40
#define NG_T2 157
#define NG_T3 67

__device__ __forceinline__ u32 pack2(float a, float b) {
    return (__float_as_uint(a) >> 16) | (__float_as_uint(b) & 0xffff0000u);
}
__device__ __forceinline__ float b2f(u16 h) { return __uint_as_float(((u32)h) << 16); }
__device__ __forceinline__ u16 f2b(float f) { return (u16)(__float_as_uint(f) >> 16); }

__device__ __forceinline__ void gload16(const void* g, void* l) {
    __builtin_amdgcn_global_load_lds(
        (const __attribute__((address_space(1))) u32*)g,
        (__attribute__((address_space(3))) u32*)l, 16, 0, 0);
}

__device__ __forceinline__ void cast8(const float* __restrict__ in, u16* __restrict__ out, size_t j) {
    const float4* p = (const float4*)(in + j * 8);
    float4 a = p[0], b = p[1];
    uint4 o = { pack2(a.x, a.y), pack2(a.z, a.w), pack2(b.x, b.y), pack2(b.z, b.w) };
    *(uint4*)(out + j * 8) = o;
}

// ======================= small prep: hidden cast + p transpose + classify + W3 pad-cast =======================
__global__ __launch_bounds__(256) void prep_small_k(
    const float* __restrict__ hidden,
    const float* __restrict__ p0, const float* __restrict__ p1,
    const float* __restrict__ p2, const float* __restrict__ p3,
    const int* __restrict__ target, const float* __restrict__ W3,
    u16* __restrict__ hb, u16* __restrict__ pTb, u16* __restrict__ W3b,
    int* __restrict__ cnt, int* __restrict__ slot,
    int* __restrict__ rowmap)
{
    int bid = blockIdx.x;
    int tid = threadIdx.x;

    if (bid < 512) {                       // hidden cast: 131072 groups of 8
        cast8(hidden, hb, bid * 256 + tid);
        return;
    }
    if (bid < 1888) {                      // p transpose -> bf16 [1360][1024]
        int b = bid - 512;
        const float* src; int d, rowOff, bx, by;
        if (b < 1024)      { src = p0; d = 1024; rowOff = 0;    bx = b & 31;          by = b >> 5; }
        else if (b < 1280) { src = p1; d = 256;  rowOff = 1024; bx = (b - 1024) & 7;  by = (b - 1024) >> 3; }
        else if (b < 1344) { src = p2; d = 64;   rowOff = 1280; bx = (b - 1280) & 1;  by = (b - 1280) >> 1; }
        else               { src = p3; d = 16;   rowOff = 1344; bx = 0;               by = b - 1344; }
        __shared__ float tile[32][33];
        int tx = tid & 31, ty = tid >> 5;
        int x = bx * 32 + tx;
        int ybase = by * 32;
#pragma unroll
        for (int j = 0; j < 4; ++j) {
            int r = ty + j * 8;
            tile[r][tx] = (x < d) ? src[(size_t)(ybase + r) * d + x] : 0.f;
        }
        __syncthreads();
#pragma unroll
        for (int j = 0; j < 4; ++j) {
            int x2 = bx * 32 + ty + j * 8;
            if (x2 < d) pTb[(size_t)(rowOff + x2) * 1024 + ybase + tx] = f2b(tile[tx][ty + j * 8]);
        }
        return;
    }
    if (bid == 1888) {
        // ---- classify block: zero rowmap, bucket targets ----
        __shared__ int lcnt[3];
        for (int i = tid; i < 3072; i += 256) rowmap[i] = 0;
        if (tid < 3) lcnt[tid] = 0;
        __syncthreads();
        for (int r = tid; r < NROWS; r += 256) {
            int t = target[r];
            int c = (t < CUT1) ? -1 : (t < CUT2) ? 0 : (t < CUT3) ? 1 : 2;
            int s = -1;
            if (c >= 0) {
                s = atomicAdd(&lcnt[c], 1);
                rowmap[c * 1024 + s] = r;
            }
            slot[r] = s;
        }
        __syncthreads();
        if (tid < 3) cnt[tid] = lcnt[tid];
        return;
    }
    // ---- W3 pad-cast: [67738][16] fp32 -> bf16 padded to ld=32 ----
    int r = (bid - 1889) * 256 + tid;
    if (r >= 67738) return;
    const float4* p = (const float4*)(W3 + (size_t)r * 16);
    float4 a = p[0], b = p[1], c = p[2], d = p[3];
    uint4 o0 = { pack2(a.x, a.y), pack2(a.z, a.w), pack2(b.x, b.y), pack2(b.z, b.w) };
    uint4 o1 = { pack2(c.x, c.y), pack2(c.z, c.w), pack2(d.x, d.y), pack2(d.z, d.w) };
    uint4 z = { 0, 0, 0, 0 };
    uint4* q = (uint4*)(W3b + (size_t)r * 32);
    q[0] = o0; q[1] = o1; q[2] = z; q[3] = z;
}
#define PREP_GRID (1889 + 265)

// ======================= MFMA GEMM body: depth-2 pipelined, 3 LDS buffers, counted vmcnt =======================
// TN: C[m][n] = sum_k A_bf16[m][k] * B[n][k]; BM=128; 4 waves 2x2 (64x64 each).
// BF32=1: B is fp32 in global; staged raw to LDS via global_load_lds in two 16B planes per
//   32B slot; converted to bf16 (pack2 truncation, bit-identical to the old cast kernel)
//   while building the MFMA B-fragments. Stage = 6 loads -> steady wait vmcnt(6).
// BF32=0: B is bf16 in global (old path). Stage = 4 loads -> vmcnt(4).
// MODE 0: store bf16 C (NCOL=1 only).
// MODE 1: pout[rbase + r] = sum over this block's cols of exp(C[r][n]+bias[n])  (NO atomics)
template<int MODE, int NCOL, int K, int BF32>
__device__ __forceinline__ void gemm_body(
    u16* __restrict__ As, u16* __restrict__ Bs, float* __restrict__ bsm,
    const u16* __restrict__ A, int lda, const int* __restrict__ rowmap,
    const void* __restrict__ Bv, int ldb,
    const float* __restrict__ bias, int N,
    u16* __restrict__ Cout, int ldc,
    float* __restrict__ pout, const int* __restrict__ count,
    int bx, int byg)
{
    constexpr int nk = K / 32;
    constexpr int total = NCOL * nk;
    constexpr int BSTRIDE = BF32 ? 8192 : 4096;   // u16 units per B buffer

    const int tid = threadIdx.x;
    const int rbase = bx * 128;
    if (MODE == 1 && count) {
        int c = *count;
        if (rbase >= ((c + 127) & ~127)) return;   // inactive slots never read downstream
    }
    const int wave = tid >> 6, lane = tid & 63;
    const int l4 = lane & 15, quad = lane >> 4;
    const int wg = (wave >> 1) * 4;   // A row16-group base
    const int cg = (wave & 1) * 4;    // B col16-group base
    const int wr = wg * 16, wc = cg * 16;

    // staging slot indices: {tid, 256+tid}
    const int g0 = tid >> 6, seg0 = (tid >> 4) & 3, r0 = tid & 15;
    const int s1i = 256 + tid;
    const int g1 = s1i >> 6, seg1 = (s1i >> 4) & 3, r1 = s1i & 15;

    const u16* Bh = (const u16*)Bv;
    const float* Bf = (const float*)Bv;

    const u16 *Asrc0, *Asrc1;
    {
        int ar0 = rbase + g0 * 16 + r0, ar1 = rbase + g1 * 16 + r1;
        if (rowmap) { ar0 = rowmap[ar0]; ar1 = rowmap[ar1]; }
        Asrc0 = A + (size_t)ar0 * lda + seg0 * 8;
        Asrc1 = A + (size_t)ar1 * lda + seg1 * 8;
    }

    // Preload bias into LDS so the epilogue issues NO vmem (keeps vmcnt stream = staging only).
    if (MODE == 1) {
        const int cb0 = byg * (NCOL * 128);
        for (int i2 = tid; i2 < NCOL * 128; i2 += 256) {
            int col = cb0 + i2;
            bsm[i2] = (col < N) ? bias[col] : 0.f;
        }
        __syncthreads();   // full fence (drains vmcnt): counts start clean at stage(0)
    }

    auto stage = [&](int s2) {
        const int buf = s2 % 3;
        const int kk = (s2 % nk) * 32;
        const int ct = s2 / nk;
        const int cb = (byg * NCOL + ct) * 128;
        int bc0 = cb + g0 * 16 + r0; if (bc0 >= N) bc0 = N - 1;
        int bc1 = cb + g1 * 16 + r1; if (bc1 >= N) bc1 = N - 1;
        u16* bA = As + buf * 4096;
        u16* bB = Bs + buf * BSTRIDE;
        gload16(Asrc0 + kk, bA + tid * 8);
        gload16(Asrc1 + kk, bA + (256 + tid) * 8);
        if constexpr (BF32) {
            // fp32: each bf16-slot (8 K-values, 32B fp32) splits into plane0 (k0..3) and plane1 (k4..7)
            const float* q0 = Bf + (size_t)bc0 * ldb + seg0 * 8 + kk;
            const float* q1 = Bf + (size_t)bc1 * ldb + seg1 * 8 + kk;
            gload16(q0,     bB + tid * 8);
            gload16(q0 + 4, bB + 4096 + tid * 8);
            gload16(q1,     bB + (256 + tid) * 8);
            gload16(q1 + 4, bB + 4096 + (256 + tid) * 8);
        } else {
            gload16(Bh + (size_t)bc0 * ldb + seg0 * 8 + kk, bB + tid * 8);
            gload16(Bh + (size_t)bc1 * ldb + seg1 * 8 + kk, bB + (256 + tid) * 8);
        }
    };

    float part[4][4];
    if (MODE == 1) {
#pragma unroll
        for (int r = 0; r < 4; ++r)
#pragma unroll
            for (int g = 0; g < 4; ++g) part[r][g] = 0.f;
    }

    stage(0);
    if (total > 1) stage(1);

    const f4 zero4 = {0.f, 0.f, 0.f, 0.f};
    f4 acc[4][4];

#pragma unroll
    for (int s = 0; s < total; ++s) {
        // wait for stage(s) to land; leave stage(s+1) (the newest loads) in flight
        if (s + 1 < total) {
            if constexpr (BF32) asm volatile("s_waitcnt vmcnt(6)" ::: "memory");
            else                asm volatile("s_waitcnt vmcnt(4)" ::: "memory");
        } else {
            asm volatile("s_waitcnt vmcnt(0)" ::: "memory");
        }
        __builtin_amdgcn_sched_barrier(0);
        __builtin_amdgcn_s_barrier();          // raw barrier: no compiler-inserted vmcnt(0) drain
        __builtin_amdgcn_sched_barrier(0);

        const int buf = s % 3;
        const u16* Ab = As + buf * 4096;
        const u16* Bb = Bs + buf * BSTRIDE;
        v8s af[4], bf[4];
#pragma unroll
        for (int r = 0; r < 4; ++r)
            af[r] = *(const v8s*)&Ab[((wg + r) * 64 + quad * 16 + l4) * 8];
        if constexpr (BF32) {
#pragma unroll
            for (int c = 0; c < 4; ++c) {
                int slt = (cg + c) * 64 + quad * 16 + l4;
                float4 f0 = *(const float4*)&Bb[slt * 8];
                float4 f1 = *(const float4*)&Bb[4096 + slt * 8];
                union { uint4 u; v8s s; } bu;
                bu.u.x = pack2(f0.x, f0.y); bu.u.y = pack2(f0.z, f0.w);
                bu.u.z = pack2(f1.x, f1.y); bu.u.w = pack2(f1.z, f1.w);
                bf[c] = bu.s;
            }
        } else {
#pragma unroll
            for (int c = 0; c < 4; ++c)
                bf[c] = *(const v8s*)&Bb[((cg + c) * 64 + quad * 16 + l4) * 8];
        }

        if (s + 2 < total) stage(s + 2);       // prefetch 2 steps ahead (different buffer)

        if ((s % nk) == 0) {
#pragma unroll
            for (int r = 0; r < 4; ++r)
#pragma unroll
                for (int c = 0; c < 4; ++c) acc[r][c] = zero4;
        }

        __builtin_amdgcn_s_setprio(1);
#pragma unroll
        for (int r = 0; r < 4; ++r)
#pragma unroll
            for (int c = 0; c < 4; ++c)
                acc[r][c] = __builtin_amdgcn_mfma_f32_16x16x32_bf16(af[r], bf[c], acc[r][c], 0, 0, 0);
        __builtin_amdgcn_s_setprio(0);

        if ((s % nk) == nk - 1) {
            const int ct = s / nk;
            const int cbase = (byg * NCOL + ct) * 128;
            if (MODE == 0) {
#pragma unroll
                for (int c = 0; c < 4; ++c) {
                    int col = cbase + wc + c * 16 + l4;
                    if (col < N) {
#pragma unroll
                        for (int r = 0; r < 4; ++r)
#pragma unroll
                            for (int g = 0; g < 4; ++g) {
                                int row = rbase + wr + r * 16 + quad * 4 + g;
                                Cout[(size_t)row * ldc + col] = f2b(acc[r][c][g]);
                            }
                    }
                }
            } else {
#pragma unroll
                for (int c = 0; c < 4; ++c) {
                    int col = cbase + wc + c * 16 + l4;
                    if (col < N) {
                        float bb = bsm[ct * 128 + wc + c * 16 + l4];
#pragma unroll
                        for (int r = 0; r < 4; ++r)
#pragma unroll
                            for (int g = 0; g < 4; ++g)
                                part[r][g] += __expf(acc[r][c][g] + bb);
                    }
                }
            }
        }
    }

    if (MODE == 1) {
        // reduce across the 16 cols held by l4
#pragma unroll
        for (int off = 1; off < 16; off <<= 1)
#pragma unroll
            for (int r = 0; r < 4; ++r)
#pragma unroll
                for (int g = 0; g < 4; ++g)
                    part[r][g] += __shfl_xor(part[r][g], off);
        float v = part[0][0];
#pragma unroll
        for (int r = 0; r < 4; ++r)
#pragma unroll
            for (int g = 0; g < 4; ++g)
                if (l4 == r * 4 + g) v = part[r][g];
        // v = col-sum for row wr + rowoff, this wave's 64-col half
        int rowoff = (l4 >> 2) * 16 + quad * 4 + (l4 & 3);   // [0,64)
        float* lbuf = (float*)As;   // 256 floats (k-loop done with As)
        __syncthreads();            // all waves done reading LDS buffers
        lbuf[(wave & 1) * 128 + wr + rowoff] = v;
        __syncthreads();
        if (tid < 128) pout[rbase + tid] = lbuf[tid] + lbuf[128 + tid];
    }
}

// ======================= proj GEMM: proj = hidden @ [p0|p1|p2|p3] =======================
// XCD-colocated: 11 col-groups padded to 16, 8 row-blocks each.
__global__ __launch_bounds__(256, 3) void projgemm_k(
    const u16* __restrict__ hb, const u16* __restrict__ pTb, u16* __restrict__ proj)
{
    __shared__ __align__(16) u16 As[3 * 4096];
    __shared__ __align__(16) u16 Bs[3 * 4096];
    int bid = blockIdx.x;
    int x = bid & 7, j = bid >> 3;          // x = XCD (round-robin), j in [0,16)
    int byg = x * 2 + (j >> 3), bx = j & 7; // 2 col-groups per XCD
    if (byg >= 11) return;
    gemm_body<0, 1, 1024, 0>(As, Bs, nullptr, hb, 1024, nullptr, pTb, 1024, nullptr, 1360,
                             proj, LDP, nullptr, nullptr, bx, byg);
}

// ======================= fused sumexp: head + 3 tails, XCD-colocated row-blocks =======================
// head/t1/t2 read W fp32 DIRECTLY (converted in-kernel); t3 reads the tiny pre-cast W3b.
// All 8 row-blocks of a col-group map to ONE XCD (its private L2 holds the B tile once).
// regions (bases all %8==0; group counts padded to multiples of 8, pad-groups exit):
//   [0,1280)    head Gp=160 (G=157) NCOL=1 K=1024 fp32
//   [1280,1600) t1   G=40           NCOL=4 K=256  fp32
//   [1600,2880) t2   Gp=160 (G=157) NCOL=8 K=64   fp32
//   [2880,3456) t3   Gp=72  (G=67)  NCOL=8 K=32   bf16 (padded)
#define SE_GRID 3456
__global__ __launch_bounds__(256, 2) void sumexp_k(
    const u16* __restrict__ proj,
    const float* __restrict__ W0, const float* __restrict__ W1,
    const float* __restrict__ W2, const u16* __restrict__ W3b,
    const float* __restrict__ b0, const float* __restrict__ b1,
    const float* __restrict__ b2, const float* __restrict__ b3,
    float* __restrict__ Ph, float* __restrict__ Pt1,
    float* __restrict__ Pt2, float* __restrict__ Pt3,
    const int* __restrict__ rmap, const int* __restrict__ cnt)
{
    __shared__ __align__(16) u16 As[3 * 4096];
    __shared__ __align__(16) u16 Bs[3 * 8192];
    __shared__ __align__(16) float bsm[1024];
    int bid = blockIdx.x;
    if (bid < 1280) {
        int x = bid & 7, j = bid >> 3;
        int byg = x * 20 + (j >> 3), bx = j & 7;
        if (byg >= NG_HEAD) return;
        gemm_body<1, 1, 1024, 1>(As, Bs, bsm, proj, LDP, nullptr, W0, 1024, b0, CUT1,
                                 nullptr, 0, Ph + (size_t)byg * 1024, nullptr, bx, byg);
    } else if (bid < 1600) {
        int rel = bid - 1280;
        int x = rel & 7, j = rel >> 3;
        int byg = x * 5 + (j >> 3), bx = j & 7;
        gemm_body<1, 4, 256, 1>(As, Bs, bsm, proj + 1024, LDP, rmap, W1, 256, b1, 20000,
                                nullptr, 0, Pt1 + (size_t)byg * 1024, cnt + 0, bx, byg);
    } else if (bid < 2880) {
        int rel = bid - 1600;
        int x = rel & 7, j = rel >> 3;
        int byg = x * 20 + (j >> 3), bx = j & 7;
        if (byg >= NG_T2) return;
        gemm_body<1, 8, 64, 1>(As, Bs, bsm, proj + 1280, LDP, rmap + 1024, W2, 64, b2, 160000,
                               nullptr, 0, Pt2 + (size_t)byg * 1024, cnt + 1, bx, byg);
    } else {
        int rel = bid - 2880;
        int x = rel & 7, j = rel >> 3;
        int byg = x * 9 + (j >> 3), bx = j & 7;
        if (byg >= NG_T3) return;
        gemm_body<1, 8, 32, 0>(As, Bs, bsm, proj + 1344, LDP, rmap + 2048, W3b, 32, b3, 67738,
                               nullptr, 0, Pt3 + (size_t)byg * 1024, cnt + 2, bx, byg);
    }
}

// ======================= fused gather + partial-reduce + finalize =======================
__global__ __launch_bounds__(256) void final_k(
    const u16* __restrict__ proj, const int* __restrict__ target, const int* __restrict__ slot,
    const float* __restrict__ cw, const float* __restrict__ cb,
    const float* __restrict__ W0, const float* __restrict__ b0,
    const float* __restrict__ W1, const float* __restrict__ b1,
    const float* __restrict__ W2, const float* __restrict__ b2,
    const float* __restrict__ W3, const float* __restrict__ b3,
    const float* __restrict__ Ph, const float* __restrict__ Pt1,
    const float* __restrict__ Pt2, const float* __restrict__ Pt3,
    float* __restrict__ out)
{
    int row = blockIdx.x * 4 + (threadIdx.x >> 6);
    int lane = threadIdx.x & 63;
    const u16* pr = proj + (size_t)row * LDP;

    // cluster logits
    float c0 = 0.f, c1 = 0.f, c2 = 0.f;
    for (int k = lane; k < 1024; k += 64) {
        float pv = b2f(pr[k]);
        c0 += pv * cw[k]; c1 += pv * cw[1024 + k]; c2 += pv * cw[2048 + k];
    }
    // head sumexp partials
    float hs = 0.f;
    for (int g = lane; g < NG_HEAD; g += 64) hs += Ph[g * 1024 + row];

    int t = target[row];
    const float* W; const float* bb; int K, off, rel;
    const float* Pc = Ph; int gc = 0;
    if (t < CUT1)      { W = W0; bb = b0; K = 1024; off = 0;    rel = t; }
    else if (t < CUT2) { W = W1; bb = b1; K = 256;  off = 1024; rel = t - CUT1; Pc = Pt1; gc = NG_T1; }
    else if (t < CUT3) { W = W2; bb = b2; K = 64;   off = 1280; rel = t - CUT2; Pc = Pt2; gc = NG_T2; }
    else               { W = W3; bb = b3; K = 16;   off = 1344; rel = t - CUT3; Pc = Pt3; gc = NG_T3; }

    // tail sumexp partials
    float ts = 0.f;
    int s = slot[row];
    if (s >= 0) {
        for (int g = lane; g < gc; g += 64) ts += Pc[g * 1024 + s];
    }
    // target logit
    float acc = 0.f;
    const float* wr = W + (size_t)rel * K;
    for (int k = lane; k < K; k += 64) acc += b2f(pr[off + k]) * wr[k];

#pragma unroll
    for (int o2 = 1; o2 < 64; o2 <<= 1) {
        c0 += __shfl_xor(c0, o2); c1 += __shfl_xor(c1, o2); c2 += __shfl_xor(c2, o2);
        hs += __shfl_xor(hs, o2); ts += __shfl_xor(ts, o2); acc += __shfl_xor(acc, o2);
    }

    if (lane == 0) {
        c0 += cb[0]; c1 += cb[1]; c2 += cb[2];
        float tl = acc + bb[rel];
        float lseh = __logf(hs + __expf(c0) + __expf(c1) + __expf(c2));
        float lp;
        if (t < CUT1) lp = tl - lseh;
        else {
            int c = (t < CUT2) ? 0 : (t < CUT3) ? 1 : 2;
            float cc = (c == 0) ? c0 : (c == 1) ? c1 : c2;
            lp = (cc - lseh) + (tl - __logf(ts));
        }
        out[row] = -lp;
    }
}

// ======================= fallback path (round-1, verified) =======================
__global__ void cast_bf16_k(const float* __restrict__ in, u16* __restrict__ out, int n8) {
    int i = blockIdx.x * 256 + threadIdx.x;
    if (i >= n8) return;
    cast8(in, out, i);
}

__global__ void transpose_f_k(const float* __restrict__ in, float* __restrict__ out, int d, int rowOff) {
    __shared__ float tile[32][33];
    int tx = threadIdx.x, ty = threadIdx.y;
    int x = blockIdx.x * 32 + tx;
    int ybase = blockIdx.y * 32;
#pragma unroll
    for (int j = 0; j < 4; ++j) {
        int r = ty + j * 8;
        tile[r][tx] = (x < d) ? in[(size_t)(ybase + r) * d + x] : 0.f;
    }
    __syncthreads();
#pragma unroll
    for (int j = 0; j < 4; ++j) {
        int x2 = blockIdx.x * 32 + ty + j * 8;
        if (x2 < d) out[(size_t)(rowOff + x2) * 1024 + ybase + tx] = tile[tx][ty + j * 8];
    }
}

__global__ __launch_bounds__(256) void gemm_tn_k(
    const u16* __restrict__ A, int lda,
    const float* __restrict__ B, int ldb,
    const float* __restrict__ bias, int N, int K,
    u16* __restrict__ Cout, int ldc, float* __restrict__ rowsum)
{
    int tid = threadIdx.x;
    int wave = tid >> 6, lane = tid & 63;
    int l4 = lane & 15, quad = lane >> 4;
    int rbase = blockIdx.x * 16;
    int cbase = blockIdx.y * 256 + wave * 64;

    f4 acc[4] = {};
    v8s zero8 = {0, 0, 0, 0, 0, 0, 0, 0};
    const u16* arow = A + (size_t)(rbase + l4) * lda;
    int nk = (K + 31) >> 5;
    for (int kt = 0; kt < nk; ++kt) {
        int kk = (kt << 5) + quad * 8;
        v8s a = (kk < K) ? *(const v8s*)(arow + kk) : zero8;
#pragma unroll
        for (int t = 0; t < 4; ++t) {
            int col = cbase + t * 16 + l4;
            v8s b = zero8;
            if ((col < N) && (kk < K)) {
                const float* bp = B + (size_t)col * ldb + kk;
                float4 f0 = *(const float4*)bp;
                float4 f1 = *(const float4*)(bp + 4);
                union { uint4 u; v8s s; } bu;
                bu.u.x = pack2(f0.x, f0.y); bu.u.y = pack2(f0.z, f0.w);
                bu.u.z = pack2(f1.x, f1.y); bu.u.w = pack2(f1.z, f1.w);
                b = bu.s;
            }
            acc[t] = __builtin_amdgcn_mfma_f32_16x16x32_bf16(a, b, acc[t], 0, 0, 0);
        }
    }
    if (Cout) {
#pragma unroll
        for (int t = 0; t < 4; ++t) {
            int col = cbase + t * 16 + l4;
            if (col < N) {
#pragma unroll
                for (int r = 0; r < 4; ++r)
                    Cout[(size_t)(rbase + quad * 4 + r) * ldc + col] = f2b(acc[t][r]);
            }
        }
    } else {
        float part[4] = {0.f, 0.f, 0.f, 0.f};
#pragma unroll
        for (int t = 0; t < 4; ++t) {
            int col = cbase + t * 16 + l4;
            if (col < N) {
                float bb = bias[col];
#pragma unroll
                for (int r = 0; r < 4; ++r) part[r] += __expf(acc[t][r] + bb);
            }
        }
#pragma unroll
        for (int off = 1; off < 16; off <<= 1)
#pragma unroll
            for (int r = 0; r < 4; ++r) part[r] += __shfl_xor(part[r], off);
        if (l4 < 4) {
            float v = (l4 == 0) ? part[0] : (l4 == 1) ? part[1] : (l4 == 2) ? part[2] : part[3];
            atomicAdd(&rowsum[rbase + quad * 4 + l4], v);
        }
    }
}

__global__ __launch_bounds__(256) void gather_k(
    const u16* __restrict__ proj, const int* __restrict__ target,
    const float* __restrict__ cw, const float* __restrict__ cb,
    const float* __restrict__ W0, const float* __restrict__ b0,
    const float* __restrict__ W1, const float* __restrict__ b1,
    const float* __restrict__ W2, const float* __restrict__ b2,
    const float* __restrict__ W3, const float* __restrict__ b3,
    float* __restrict__ rs_head, float* __restrict__ cl, float* __restrict__ tl)
{
    int row = blockIdx.x * 4 + (threadIdx.x >> 6);
    int lane = threadIdx.x & 63;
    const u16* pr = proj + (size_t)row * LDP;

    float c0 = 0.f, c1 = 0.f, c2 = 0.f;
    for (int k = lane; k < 1024; k += 64) {
        float pv = b2f(pr[k]);
        c0 += pv * cw[k]; c1 += pv * cw[1024 + k]; c2 += pv * cw[2048 + k];
    }
#pragma unroll
    for (int off = 1; off < 64; off <<= 1) {
        c0 += __shfl_xor(c0, off); c1 += __shfl_xor(c1, off); c2 += __shfl_xor(c2, off);
    }
    int t = target[row];
    const float* W; const float* bb; int K, off, rel;
    if (t < CUT1)      { W = W0; bb = b0; K = 1024; off = 0;    rel = t; }
    else if (t < CUT2) { W = W1; bb = b1; K = 256;  off = 1024; rel = t - CUT1; }
    else if (t < CUT3) { W = W2; bb = b2; K = 64;   off = 1280; rel = t - CUT2; }
    else               { W = W3; bb = b3; K = 16;   off = 1344; rel = t - CUT3; }
    float acc = 0.f;
    const float* wr = W + (size_t)rel * K;
    for (int k = lane; k < K; k += 64) acc += b2f(pr[off + k]) * wr[k];
#pragma unroll
    for (int o2 = 1; o2 < 64; o2 <<= 1) acc += __shfl_xor(acc, o2);
    if (lane == 0) {
        c0 += cb[0]; c1 += cb[1]; c2 += cb[2];
        cl[row * 3 + 0] = c0; cl[row * 3 + 1] = c1; cl[row * 3 + 2] = c2;
        atomicAdd(&rs_head[row], __expf(c0) + __expf(c1) + __expf(c2));
        tl[row] = acc + bb[rel];
    }
}

__global__ void finalize_full_k(const int* __restrict__ target, const float* __restrict__ rs,
                                const float* __restrict__ cl, const float* __restrict__ tl,
                                float* __restrict__ out)
{
    int i = blockIdx.x * 256 + threadIdx.x;
    if (i >= NROWS) return;
    int t = target[i];
    float lseh = __logf(rs[i]);
    float lp;
    if (t < CUT1) lp = tl[i] - lseh;
    else {
        int c = (t < CUT2) ? 0 : (t < CUT3) ? 1 : 2;
        lp = (cl[i * 3 + c] - lseh) + (tl[i] - __logf(rs[(c + 1) * 1024 + i]));
    }
    out[i] = -lp;
}

// ======================= host =======================
extern "C" void kernel_launch(void* const* d_in, const int* in_sizes, int n_in,
                              void* d_out, int out_size, void* d_ws, size_t ws_size,
                              hipStream_t stream)
{
    const float* hidden = (const float*)d_in[0];
    const int*   target = (const int*)d_in[1];
    const float* W0 = (const float*)d_in[2];
    const float* b0 = (const float*)d_in[3];
    const float* p0 = (const float*)d_in[4];
    const float* W1 = (const float*)d_in[5];
    const float* b1 = (const float*)d_in[6];
    const float* p1 = (const float*)d_in[7];
    const float* W2 = (const float*)d_in[8];
    const float* b2 = (const float*)d_in[9];
    const float* p2 = (const float*)d_in[10];
    const float* W3 = (const float*)d_in[11];
    const float* b3 = (const float*)d_in[12];
    const float* p3 = (const float*)d_in[13];
    const float* cw = (const float*)d_in[14];
    const float* cb = (const float*)d_in[15];
    float* out = (float*)d_out;
    char* w = (char*)d_ws;

    if (ws_size >= 84000000ull) {
        // ---- fast path ----
        // phase A buffers (prep/projgemm): hb [0,2097152), pTb [2097152,4882432)
        // phase B buffers (sumexp/final): partials recycle the hb/pTb region
        u16*   hb   = (u16*)(w + 0);             // 1024x1024 bf16
        u16*   pTb  = (u16*)(w + 2097152);       // [1360][1024] bf16
        float* Ph   = (float*)(w + 0);           // [157][1024] f32 (recycles hb)
        float* Pt1  = (float*)(w + 643072);      // [40][1024]
        float* Pt2  = (float*)(w + 806912);      // [157][1024]
        float* Pt3  = (float*)(w + 1449984);     // [67][1024]   (ends 1724416 < 2097152)
        u16*   proj = (u16*)(w + 4882432);       // [1024][1360] bf16
        u16*   W3b  = (u16*)(w + 79341568);      // 67738x32 (zero-padded k16..31)
        int*   cnt  = (int*)(w + 83693184);      // 3 (+pad)
        int*   slot = (int*)(w + 83693200);      // 1024
        int*   rmap = (int*)(w + 83697296);      // 3x1024

        prep_small_k<<<PREP_GRID, 256, 0, stream>>>(hidden, p0, p1, p2, p3, target, W3,
                                                    hb, pTb, W3b, cnt, slot, rmap);

        projgemm_k<<<128, 256, 0, stream>>>(hb, pTb, proj);

        sumexp_k<<<SE_GRID, 256, 0, stream>>>(proj, W0, W1, W2, W3b,
                                              b0, b1, b2, b3,
                                              Ph, Pt1, Pt2, Pt3, rmap, cnt);

        final_k<<<256, 256, 0, stream>>>(proj, target, slot, cw, cb,
                                         W0, b0, W1, b1, W2, b2, W3, b3,
                                         Ph, Pt1, Pt2, Pt3, out);
    } else {
        // ---- round-1 verified fallback ----
        float* pT   = (float*)w;                          // [1360][1024] f32
        u16*   hb   = (u16*)(w + 5570560);                // [1024][1024] bf16
        u16*   proj = (u16*)(w + 7667712);                // [1024][1360] bf16
        float* rs   = (float*)(w + 10452992);
        float* cl   = (float*)(w + 10469376);
        float* tl   = (float*)(w + 10481664);
        dim3 tb(32, 8);

        hipMemsetAsync(rs, 0, 4 * 1024 * sizeof(float), stream);
        cast_bf16_k<<<512, 256, 0, stream>>>(hidden, hb, 131072);
        transpose_f_k<<<dim3(32, 32), tb, 0, stream>>>(p0, pT, 1024, 0);
        transpose_f_k<<<dim3(8, 32),  tb, 0, stream>>>(p1, pT, 256, 1024);
        transpose_f_k<<<dim3(2, 32),  tb, 0, stream>>>(p2, pT, 64, 1280);
        transpose_f_k<<<dim3(1, 32),  tb, 0, stream>>>(p3, pT, 16, 1344);

        gemm_tn_k<<<dim3(64, 6), 256, 0, stream>>>(hb, 1024, pT, 1024, nullptr,
                                                   1360, 1024, proj, LDP, nullptr);
        gemm_tn_k<<<dim3(64, 79), 256, 0, stream>>>(proj, LDP, W0, 1024, b0,
                                                    CUT1, 1024, nullptr, 0, rs);
        gemm_tn_k<<<dim3(64, 79), 256, 0, stream>>>(proj + 1024, LDP, W1, 256, b1,
                                                    20000, 256, nullptr, 0, rs + 1024);
        gemm_tn_k<<<dim3(64, 625), 256, 0, stream>>>(proj + 1280, LDP, W2, 64, b2,
                                                     160000, 64, nullptr, 0, rs + 2048);
        gemm_tn_k<<<dim3(64, 265), 256, 0, stream>>>(proj + 1344, LDP, W3, 16, b3,
                                                     67738, 16, nullptr, 0, rs + 3072);

        gather_k<<<256, 256, 0, stream>>>(proj, target, cw, cb,
                                          W0, b0, W1, b1, W2, b2, W3, b3, rs, cl, tl);
        finalize_full_k<<<4, 256, 0, stream>>>(target, rs, cl, tl, out);
    }
}

// Round 3
// 354.965 us; speedup vs baseline: 1.1677x; 1.1677x over previous
//
#include <hip/hip_runtime.h>
#include <stdint.h>

typedef short v8s __attribute__((ext_vector_type(8)));
typedef float f4 __attribute__((ext_vector_type(4)));
typedef unsigned short u16;
typedef unsigned int u32;

#define CUT1 19997
#define CUT2 39997
#define CUT3 199997
#define NROWS 1024
#define LDP 1360   // packed proj cols: 1024 + 256 + 64 + 16

#define NG_HEAD 157
#define NG_T1 40
#define NG_T2 157
#define NG_T3 67

__device__ __forceinline__ u32 pack2(float a, float b) {
    return (__float_as_uint(a) >> 16) | (__float_as_uint(b) & 0xffff0000u);
}
__device__ __forceinline__ float b2f(u16 h) { return __uint_as_float(((u32)h) << 16); }
__device__ __forceinline__ u16 f2b(float f) { return (u16)(__float_as_uint(f) >> 16); }

__device__ __forceinline__ void gload16(const void* g, void* l) {
    __builtin_amdgcn_global_load_lds(
        (const __attribute__((address_space(1))) u32*)g,
        (__attribute__((address_space(3))) u32*)l, 16, 0, 0);
}

__device__ __forceinline__ void cast8(const float* __restrict__ in, u16* __restrict__ out, size_t j) {
    const float4* p = (const float4*)(in + j * 8);
    float4 a = p[0], b = p[1];
    uint4 o = { pack2(a.x, a.y), pack2(a.z, a.w), pack2(b.x, b.y), pack2(b.z, b.w) };
    *(uint4*)(out + j * 8) = o;
}

// ======================= small prep: hidden cast + p transpose + classify =======================
__global__ __launch_bounds__(256) void prep_small_k(
    const float* __restrict__ hidden,
    const float* __restrict__ p0, const float* __restrict__ p1,
    const float* __restrict__ p2, const float* __restrict__ p3,
    const int* __restrict__ target,
    u16* __restrict__ hb, u16* __restrict__ pTb,
    int* __restrict__ cnt, int* __restrict__ slot,
    int* __restrict__ rowmap)
{
    int bid = blockIdx.x;
    int tid = threadIdx.x;

    if (bid < 512) {                       // hidden cast: 131072 groups of 8
        cast8(hidden, hb, bid * 256 + tid);
        return;
    }
    if (bid < 1888) {                      // p transpose -> bf16 [1360][1024]
        int b = bid - 512;
        const float* src; int d, rowOff, bx, by;
        if (b < 1024)      { src = p0; d = 1024; rowOff = 0;    bx = b & 31;          by = b >> 5; }
        else if (b < 1280) { src = p1; d = 256;  rowOff = 1024; bx = (b - 1024) & 7;  by = (b - 1024) >> 3; }
        else if (b < 1344) { src = p2; d = 64;   rowOff = 1280; bx = (b - 1280) & 1;  by = (b - 1280) >> 1; }
        else               { src = p3; d = 16;   rowOff = 1344; bx = 0;               by = b - 1344; }
        __shared__ float tile[32][33];
        int tx = tid & 31, ty = tid >> 5;
        int x = bx * 32 + tx;
        int ybase = by * 32;
#pragma unroll
        for (int j = 0; j < 4; ++j) {
            int r = ty + j * 8;
            tile[r][tx] = (x < d) ? src[(size_t)(ybase + r) * d + x] : 0.f;
        }
        __syncthreads();
#pragma unroll
        for (int j = 0; j < 4; ++j) {
            int x2 = bx * 32 + ty + j * 8;
            if (x2 < d) pTb[(size_t)(rowOff + x2) * 1024 + ybase + tx] = f2b(tile[tx][ty + j * 8]);
        }
        return;
    }

    // ---- classify block: zero rowmap, bucket targets ----
    __shared__ int lcnt[3];
    for (int i = tid; i < 3072; i += 256) rowmap[i] = 0;
    if (tid < 3) lcnt[tid] = 0;
    __syncthreads();
    for (int r = tid; r < NROWS; r += 256) {
        int t = target[r];
        int c = (t < CUT1) ? -1 : (t < CUT2) ? 0 : (t < CUT3) ? 1 : 2;
        int s = -1;
        if (c >= 0) {
            s = atomicAdd(&lcnt[c], 1);
            rowmap[c * 1024 + s] = r;
        }
        slot[r] = s;
    }
    __syncthreads();
    if (tid < 3) cnt[tid] = lcnt[tid];
}

// ======================= MFMA GEMM body: 8 waves (512 thr), depth-2 pipeline, counted vmcnt ===========
// TN: C[m][n] = sum_k A_bf16[m][k] * B_bf16[n][k]; BM=128; 8 waves 2x4 (64x32 tile each).
// Flattened (ct,kk) step loop; step s reads buf s%3 while staging step s+2 into (s+2)%3.
// Each thread stages exactly ONE 16B slot per operand -> steady-state wait vmcnt(2).
// MODE 0: store bf16 C (NCOL=1 only).
// MODE 1: pout[rbase + r] = sum over this block's cols of exp(C[r][n]+bias[n])  (NO atomics)
template<int MODE, int NCOL, int K>
__device__ __forceinline__ void gemm_body(
    u16* __restrict__ As, u16* __restrict__ Bs, float* __restrict__ bsm,
    const u16* __restrict__ A, int lda, const int* __restrict__ rowmap,
    const u16* __restrict__ B, int ldb,
    const float* __restrict__ bias, int N,
    u16* __restrict__ Cout, int ldc,
    float* __restrict__ pout, const int* __restrict__ count,
    int bx, int byg)
{
    constexpr int nk = K / 32;
    constexpr int total = NCOL * nk;

    const int tid = threadIdx.x;
    const int rbase = bx * 128;
    if (MODE == 1 && count) {
        int c = *count;
        if (rbase >= ((c + 127) & ~127)) return;   // inactive slots never read downstream
    }
    const int wave = tid >> 6, lane = tid & 63;
    const int l4 = lane & 15, quad = lane >> 4;
    const int wrow = wave >> 2;       // 0..1  (64-row half)
    const int wcol = wave & 3;        // 0..3  (32-col strip)
    const int wg = wrow * 4;          // A row16-group base
    const int cg = wcol * 2;          // B col16-group base
    const int wr = wg * 16, wc = cg * 16;

    // staging slot index = tid (512 slots = 128 rows x 4 segs)
    const int g0 = tid >> 6, seg0 = (tid >> 4) & 3, r0 = tid & 15;

    const u16* Asrc0;
    {
        int ar0 = rbase + g0 * 16 + r0;
        if (rowmap) ar0 = rowmap[ar0];
        Asrc0 = A + (size_t)ar0 * lda + seg0 * 8;
    }

    // Preload bias into LDS so the epilogue issues NO vmem (keeps vmcnt stream = staging only).
    if (MODE == 1) {
        const int cb0 = byg * (NCOL * 128);
        for (int i2 = tid; i2 < NCOL * 128; i2 += 512) {
            int col = cb0 + i2;
            bsm[i2] = (col < N) ? bias[col] : 0.f;
        }
        __syncthreads();   // full fence (drains vmcnt): counts start clean at stage(0)
    }

    auto stage = [&](int s2) {
        const int buf = s2 % 3;
        const int kk = (s2 % nk) * 32;
        const int ct = s2 / nk;
        const int cb = (byg * NCOL + ct) * 128;
        int bc0 = cb + g0 * 16 + r0; if (bc0 >= N) bc0 = N - 1;
        u16* bA = As + buf * 4096;
        u16* bB = Bs + buf * 4096;
        gload16(Asrc0 + kk, bA + tid * 8);
        gload16(B + (size_t)bc0 * ldb + seg0 * 8 + kk, bB + tid * 8);
    };

    float part[4][4];
    if (MODE == 1) {
#pragma unroll
        for (int r = 0; r < 4; ++r)
#pragma unroll
            for (int g = 0; g < 4; ++g) part[r][g] = 0.f;
    }

    stage(0);
    if (total > 1) stage(1);

    const f4 zero4 = {0.f, 0.f, 0.f, 0.f};
    f4 acc[4][2];

#pragma unroll
    for (int s = 0; s < total; ++s) {
        // wait for stage(s) to land; leave stage(s+1) (the 2 newest loads) in flight
        if (s + 1 < total) asm volatile("s_waitcnt vmcnt(2)" ::: "memory");
        else               asm volatile("s_waitcnt vmcnt(0)" ::: "memory");
        __builtin_amdgcn_sched_barrier(0);
        __builtin_amdgcn_s_barrier();          // raw barrier: no compiler-inserted vmcnt(0) drain
        __builtin_amdgcn_sched_barrier(0);

        const int buf = s % 3;
        const u16* Ab = As + buf * 4096;
        const u16* Bb = Bs + buf * 4096;
        v8s af[4], bf[2];
#pragma unroll
        for (int r = 0; r < 4; ++r)
            af[r] = *(const v8s*)&Ab[((wg + r) * 64 + quad * 16 + l4) * 8];
#pragma unroll
        for (int c = 0; c < 2; ++c)
            bf[c] = *(const v8s*)&Bb[((cg + c) * 64 + quad * 16 + l4) * 8];

        if (s + 2 < total) stage(s + 2);       // prefetch 2 steps ahead (different buffer)

        if ((s % nk) == 0) {
#pragma unroll
            for (int r = 0; r < 4; ++r)
#pragma unroll
                for (int c = 0; c < 2; ++c) acc[r][c] = zero4;
        }

        __builtin_amdgcn_s_setprio(1);
#pragma unroll
        for (int r = 0; r < 4; ++r)
#pragma unroll
            for (int c = 0; c < 2; ++c)
                acc[r][c] = __builtin_amdgcn_mfma_f32_16x16x32_bf16(af[r], bf[c], acc[r][c], 0, 0, 0);
        __builtin_amdgcn_s_setprio(0);

        if ((s % nk) == nk - 1) {
            const int ct = s / nk;
            const int cbase = (byg * NCOL + ct) * 128;
            if (MODE == 0) {
#pragma unroll
                for (int c = 0; c < 2; ++c) {
                    int col = cbase + wc + c * 16 + l4;
                    if (col < N) {
#pragma unroll
                        for (int r = 0; r < 4; ++r)
#pragma unroll
                            for (int g = 0; g < 4; ++g) {
                                int row = rbase + wr + r * 16 + quad * 4 + g;
                                Cout[(size_t)row * ldc + col] = f2b(acc[r][c][g]);
                            }
                    }
                }
            } else {
#pragma unroll
                for (int c = 0; c < 2; ++c) {
                    int col = cbase + wc + c * 16 + l4;
                    if (col < N) {
                        float bb = bsm[ct * 128 + wc + c * 16 + l4];
#pragma unroll
                        for (int r = 0; r < 4; ++r)
#pragma unroll
                            for (int g = 0; g < 4; ++g)
                                part[r][g] += __expf(acc[r][c][g] + bb);
                    }
                }
            }
        }
    }

    if (MODE == 1) {
        // reduce across the 16 cols held by l4
#pragma unroll
        for (int off = 1; off < 16; off <<= 1)
#pragma unroll
            for (int r = 0; r < 4; ++r)
#pragma unroll
                for (int g = 0; g < 4; ++g)
                    part[r][g] += __shfl_xor(part[r][g], off);
        float v = part[0][0];
#pragma unroll
        for (int r = 0; r < 4; ++r)
#pragma unroll
            for (int g = 0; g < 4; ++g)
                if (l4 == r * 4 + g) v = part[r][g];
        // v = col-sum for row (wr + rowoff) over this wave's 32-col strip
        int rowoff = (l4 >> 2) * 16 + quad * 4 + (l4 & 3);   // [0,64)
        float* lbuf = (float*)As;   // 512 floats (k-loop done with As)
        __syncthreads();            // all waves done reading LDS buffers
        lbuf[wcol * 128 + wr + rowoff] = v;
        __syncthreads();
        if (tid < 128)
            pout[rbase + tid] = (lbuf[tid] + lbuf[128 + tid]) + (lbuf[256 + tid] + lbuf[384 + tid]);
    }
}

// ======================= fused W-cast + proj GEMM (512 threads) =======================
// blocks [0,128): proj = hidden @ [p0|p1|p2|p3] (XCD-colocated, 11 col-groups padded to 16);
// [128,9010): W0..W3 fp32->bf16 casts (groups of 8 elems, 512 threads/block)
#define CP_E0 2559616
#define CP_E1 3199616
#define CP_E2 4479616
#define CP_GRID 9010
__global__ __launch_bounds__(512, 2) void castproj_k(
    const u16* __restrict__ hb, const u16* __restrict__ pTb, u16* __restrict__ proj,
    const float* __restrict__ W0, const float* __restrict__ W1,
    const float* __restrict__ W2, const float* __restrict__ W3,
    u16* __restrict__ W0b, u16* __restrict__ W1b,
    u16* __restrict__ W2b, u16* __restrict__ W3b)
{
    __shared__ __align__(16) u16 As[3 * 4096];
    __shared__ __align__(16) u16 Bs[3 * 4096];
    int bid = blockIdx.x;
    if (bid < 128) {
        int x = bid & 7, j = bid >> 3;          // x = XCD (round-robin), j in [0,16)
        int byg = x * 2 + (j >> 3), bx = j & 7; // 2 col-groups per XCD
        if (byg >= 11) return;
        gemm_body<0, 1, 1024>(As, Bs, nullptr, hb, 1024, nullptr, pTb, 1024, nullptr, 1360,
                              proj, LDP, nullptr, nullptr, bx, byg);
        return;
    }
    int i = (bid - 128) * 512 + threadIdx.x;
    if (i < CP_E0) { cast8(W0, W0b, i); return; }
    if (i < CP_E1) { cast8(W1, W1b, i - CP_E0); return; }
    if (i < CP_E2) { cast8(W2, W2b, i - CP_E1); return; }
    int r = i - CP_E2;
    if (r >= 67738) return;
    // W3 [67738][16] -> bf16 padded to ld=32
    const float4* p = (const float4*)(W3 + (size_t)r * 16);
    float4 a = p[0], b = p[1], c = p[2], d = p[3];
    uint4 o0 = { pack2(a.x, a.y), pack2(a.z, a.w), pack2(b.x, b.y), pack2(b.z, b.w) };
    uint4 o1 = { pack2(c.x, c.y), pack2(c.z, c.w), pack2(d.x, d.y), pack2(d.z, d.w) };
    uint4 z = { 0, 0, 0, 0 };
    uint4* q = (uint4*)(W3b + (size_t)r * 32);
    q[0] = o0; q[1] = o1; q[2] = z; q[3] = z;
}

// ======================= fused sumexp: head + 3 tails, XCD-colocated row-blocks =======================
// All 8 row-blocks of a col-group map to ONE XCD (its private L2 holds the B tile once).
// regions (bases all %8==0; group counts padded to multiples of 8, pad-groups exit):
//   [0,1280)    head Gp=160 (G=157) NCOL=1 K=1024
//   [1280,1600) t1   G=40           NCOL=4 K=256
//   [1600,2880) t2   Gp=160 (G=157) NCOL=8 K=64
//   [2880,3456) t3   Gp=72  (G=67)  NCOL=8 K=32
#define SE_GRID 3456
__global__ __launch_bounds__(512, 4) void sumexp_k(
    const u16* __restrict__ proj,
    const u16* __restrict__ W0b, const u16* __restrict__ W1b,
    const u16* __restrict__ W2b, const u16* __restrict__ W3b,
    const float* __restrict__ b0, const float* __restrict__ b1,
    const float* __restrict__ b2, const float* __restrict__ b3,
    float* __restrict__ Ph, float* __restrict__ Pt1,
    float* __restrict__ Pt2, float* __restrict__ Pt3,
    const int* __restrict__ rmap, const int* __restrict__ cnt)
{
    __shared__ __align__(16) u16 As[3 * 4096];
    __shared__ __align__(16) u16 Bs[3 * 4096];
    __shared__ __align__(16) float bsm[1024];
    int bid = blockIdx.x;
    if (bid < 1280) {
        int x = bid & 7, j = bid >> 3;
        int byg = x * 20 + (j >> 3), bx = j & 7;
        if (byg >= NG_HEAD) return;
        gemm_body<1, 1, 1024>(As, Bs, bsm, proj, LDP, nullptr, W0b, 1024, b0, CUT1,
                              nullptr, 0, Ph + (size_t)byg * 1024, nullptr, bx, byg);
    } else if (bid < 1600) {
        int rel = bid - 1280;
        int x = rel & 7, j = rel >> 3;
        int byg = x * 5 + (j >> 3), bx = j & 7;
        gemm_body<1, 4, 256>(As, Bs, bsm, proj + 1024, LDP, rmap, W1b, 256, b1, 20000,
                             nullptr, 0, Pt1 + (size_t)byg * 1024, cnt + 0, bx, byg);
    } else if (bid < 2880) {
        int rel = bid - 1600;
        int x = rel & 7, j = rel >> 3;
        int byg = x * 20 + (j >> 3), bx = j & 7;
        if (byg >= NG_T2) return;
        gemm_body<1, 8, 64>(As, Bs, bsm, proj + 1280, LDP, rmap + 1024, W2b, 64, b2, 160000,
                            nullptr, 0, Pt2 + (size_t)byg * 1024, cnt + 1, bx, byg);
    } else {
        int rel = bid - 2880;
        int x = rel & 7, j = rel >> 3;
        int byg = x * 9 + (j >> 3), bx = j & 7;
        if (byg >= NG_T3) return;
        gemm_body<1, 8, 32>(As, Bs, bsm, proj + 1344, LDP, rmap + 2048, W3b, 32, b3, 67738,
                            nullptr, 0, Pt3 + (size_t)byg * 1024, cnt + 2, bx, byg);
    }
}

// ======================= fused gather + partial-reduce + finalize =======================
__global__ __launch_bounds__(256) void final_k(
    const u16* __restrict__ proj, const int* __restrict__ target, const int* __restrict__ slot,
    const float* __restrict__ cw, const float* __restrict__ cb,
    const float* __restrict__ W0, const float* __restrict__ b0,
    const float* __restrict__ W1, const float* __restrict__ b1,
    const float* __restrict__ W2, const float* __restrict__ b2,
    const float* __restrict__ W3, const float* __restrict__ b3,
    const float* __restrict__ Ph, const float* __restrict__ Pt1,
    const float* __restrict__ Pt2, const float* __restrict__ Pt3,
    float* __restrict__ out)
{
    int row = blockIdx.x * 4 + (threadIdx.x >> 6);
    int lane = threadIdx.x & 63;
    const u16* pr = proj + (size_t)row * LDP;

    // cluster logits
    float c0 = 0.f, c1 = 0.f, c2 = 0.f;
    for (int k = lane; k < 1024; k += 64) {
        float pv = b2f(pr[k]);
        c0 += pv * cw[k]; c1 += pv * cw[1024 + k]; c2 += pv * cw[2048 + k];
    }
    // head sumexp partials
    float hs = 0.f;
    for (int g = lane; g < NG_HEAD; g += 64) hs += Ph[g * 1024 + row];

    int t = target[row];
    const float* W; const float* bb; int K, off, rel;
    const float* Pc = Ph; int gc = 0;
    if (t < CUT1)      { W = W0; bb = b0; K = 1024; off = 0;    rel = t; }
    else if (t < CUT2) { W = W1; bb = b1; K = 256;  off = 1024; rel = t - CUT1; Pc = Pt1; gc = NG_T1; }
    else if (t < CUT3) { W = W2; bb = b2; K = 64;   off = 1280; rel = t - CUT2; Pc = Pt2; gc = NG_T2; }
    else               { W = W3; bb = b3; K = 16;   off = 1344; rel = t - CUT3; Pc = Pt3; gc = NG_T3; }

    // tail sumexp partials
    float ts = 0.f;
    int s = slot[row];
    if (s >= 0) {
        for (int g = lane; g < gc; g += 64) ts += Pc[g * 1024 + s];
    }
    // target logit
    float acc = 0.f;
    const float* wr = W + (size_t)rel * K;
    for (int k = lane; k < K; k += 64) acc += b2f(pr[off + k]) * wr[k];

#pragma unroll
    for (int o2 = 1; o2 < 64; o2 <<= 1) {
        c0 += __shfl_xor(c0, o2); c1 += __shfl_xor(c1, o2); c2 += __shfl_xor(c2, o2);
        hs += __shfl_xor(hs, o2); ts += __shfl_xor(ts, o2); acc += __shfl_xor(acc, o2);
    }

    if (lane == 0) {
        c0 += cb[0]; c1 += cb[1]; c2 += cb[2];
        float tl = acc + bb[rel];
        float lseh = __logf(hs + __expf(c0) + __expf(c1) + __expf(c2));
        float lp;
        if (t < CUT1) lp = tl - lseh;
        else {
            int c = (t < CUT2) ? 0 : (t < CUT3) ? 1 : 2;
            float cc = (c == 0) ? c0 : (c == 1) ? c1 : c2;
            lp = (cc - lseh) + (tl - __logf(ts));
        }
        out[row] = -lp;
    }
}

// ======================= fallback path (round-1, verified) =======================
__global__ void cast_bf16_k(const float* __restrict__ in, u16* __restrict__ out, int n8) {
    int i = blockIdx.x * 256 + threadIdx.x;
    if (i >= n8) return;
    cast8(in, out, i);
}

__global__ void transpose_f_k(const float* __restrict__ in, float* __restrict__ out, int d, int rowOff) {
    __shared__ float tile[32][33];
    int tx = threadIdx.x, ty = threadIdx.y;
    int x = blockIdx.x * 32 + tx;
    int ybase = blockIdx.y * 32;
#pragma unroll
    for (int j = 0; j < 4; ++j) {
        int r = ty + j * 8;
        tile[r][tx] = (x < d) ? in[(size_t)(ybase + r) * d + x] : 0.f;
    }
    __syncthreads();
#pragma unroll
    for (int j = 0; j < 4; ++j) {
        int x2 = blockIdx.x * 32 + ty + j * 8;
        if (x2 < d) out[(size_t)(rowOff + x2) * 1024 + ybase + tx] = tile[tx][ty + j * 8];
    }
}

__global__ __launch_bounds__(256) void gemm_tn_k(
    const u16* __restrict__ A, int lda,
    const float* __restrict__ B, int ldb,
    const float* __restrict__ bias, int N, int K,
    u16* __restrict__ Cout, int ldc, float* __restrict__ rowsum)
{
    int tid = threadIdx.x;
    int wave = tid >> 6, lane = tid & 63;
    int l4 = lane & 15, quad = lane >> 4;
    int rbase = blockIdx.x * 16;
    int cbase = blockIdx.y * 256 + wave * 64;

    f4 acc[4] = {};
    v8s zero8 = {0, 0, 0, 0, 0, 0, 0, 0};
    const u16* arow = A + (size_t)(rbase + l4) * lda;
    int nk = (K + 31) >> 5;
    for (int kt = 0; kt < nk; ++kt) {
        int kk = (kt << 5) + quad * 8;
        v8s a = (kk < K) ? *(const v8s*)(arow + kk) : zero8;
#pragma unroll
        for (int t = 0; t < 4; ++t) {
            int col = cbase + t * 16 + l4;
            v8s b = zero8;
            if ((col < N) && (kk < K)) {
                const float* bp = B + (size_t)col * ldb + kk;
                float4 f0 = *(const float4*)bp;
                float4 f1 = *(const float4*)(bp + 4);
                union { uint4 u; v8s s; } bu;
                bu.u.x = pack2(f0.x, f0.y); bu.u.y = pack2(f0.z, f0.w);
                bu.u.z = pack2(f1.x, f1.y); bu.u.w = pack2(f1.z, f1.w);
                b = bu.s;
            }
            acc[t] = __builtin_amdgcn_mfma_f32_16x16x32_bf16(a, b, acc[t], 0, 0, 0);
        }
    }
    if (Cout) {
#pragma unroll
        for (int t = 0; t < 4; ++t) {
            int col = cbase + t * 16 + l4;
            if (col < N) {
#pragma unroll
                for (int r = 0; r < 4; ++r)
                    Cout[(size_t)(rbase + quad * 4 + r) * ldc + col] = f2b(acc[t][r]);
            }
        }
    } else {
        float part[4] = {0.f, 0.f, 0.f, 0.f};
#pragma unroll
        for (int t = 0; t < 4; ++t) {
            int col = cbase + t * 16 + l4;
            if (col < N) {
                float bb = bias[col];
#pragma unroll
                for (int r = 0; r < 4; ++r) part[r] += __expf(acc[t][r] + bb);
            }
        }
#pragma unroll
        for (int off = 1; off < 16; off <<= 1)
#pragma unroll
            for (int r = 0; r < 4; ++r) part[r] += __shfl_xor(part[r], off);
        if (l4 < 4) {
            float v = (l4 == 0) ? part[0] : (l4 == 1) ? part[1] : (l4 == 2) ? part[2] : part[3];
            atomicAdd(&rowsum[rbase + quad * 4 + l4], v);
        }
    }
}

__global__ __launch_bounds__(256) void gather_k(
    const u16* __restrict__ proj, const int* __restrict__ target,
    const float* __restrict__ cw, const float* __restrict__ cb,
    const float* __restrict__ W0, const float* __restrict__ b0,
    const float* __restrict__ W1, const float* __restrict__ b1,
    const float* __restrict__ W2, const float* __restrict__ b2,
    const float* __restrict__ W3, const float* __restrict__ b3,
    float* __restrict__ rs_head, float* __restrict__ cl, float* __restrict__ tl)
{
    int row = blockIdx.x * 4 + (threadIdx.x >> 6);
    int lane = threadIdx.x & 63;
    const u16* pr = proj + (size_t)row * LDP;

    float c0 = 0.f, c1 = 0.f, c2 = 0.f;
    for (int k = lane; k < 1024; k += 64) {
        float pv = b2f(pr[k]);
        c0 += pv * cw[k]; c1 += pv * cw[1024 + k]; c2 += pv * cw[2048 + k];
    }
#pragma unroll
    for (int off = 1; off < 64; off <<= 1) {
        c0 += __shfl_xor(c0, off); c1 += __shfl_xor(c1, off); c2 += __shfl_xor(c2, off);
    }
    int t = target[row];
    const float* W; const float* bb; int K, off, rel;
    if (t < CUT1)      { W = W0; bb = b0; K = 1024; off = 0;    rel = t; }
    else if (t < CUT2) { W = W1; bb = b1; K = 256;  off = 1024; rel = t - CUT1; }
    else if (t < CUT3) { W = W2; bb = b2; K = 64;   off = 1280; rel = t - CUT2; }
    else               { W = W3; bb = b3; K = 16;   off = 1344; rel = t - CUT3; }
    float acc = 0.f;
    const float* wr = W + (size_t)rel * K;
    for (int k = lane; k < K; k += 64) acc += b2f(pr[off + k]) * wr[k];
#pragma unroll
    for (int o2 = 1; o2 < 64; o2 <<= 1) acc += __shfl_xor(acc, o2);
    if (lane == 0) {
        c0 += cb[0]; c1 += cb[1]; c2 += cb[2];
        cl[row * 3 + 0] = c0; cl[row * 3 + 1] = c1; cl[row * 3 + 2] = c2;
        atomicAdd(&rs_head[row], __expf(c0) + __expf(c1) + __expf(c2));
        tl[row] = acc + bb[rel];
    }
}

__global__ void finalize_full_k(const int* __restrict__ target, const float* __restrict__ rs,
                                const float* __restrict__ cl, const float* __restrict__ tl,
                                float* __restrict__ out)
{
    int i = blockIdx.x * 256 + threadIdx.x;
    if (i >= NROWS) return;
    int t = target[i];
    float lseh = __logf(rs[i]);
    float lp;
    if (t < CUT1) lp = tl[i] - lseh;
    else {
        int c = (t < CUT2) ? 0 : (t < CUT3) ? 1 : 2;
        lp = (cl[i * 3 + c] - lseh) + (tl[i] - __logf(rs[(c + 1) * 1024 + i]));
    }
    out[i] = -lp;
}

// ======================= host =======================
extern "C" void kernel_launch(void* const* d_in, const int* in_sizes, int n_in,
                              void* d_out, int out_size, void* d_ws, size_t ws_size,
                              hipStream_t stream)
{
    const float* hidden = (const float*)d_in[0];
    const int*   target = (const int*)d_in[1];
    const float* W0 = (const float*)d_in[2];
    const float* b0 = (const float*)d_in[3];
    const float* p0 = (const float*)d_in[4];
    const float* W1 = (const float*)d_in[5];
    const float* b1 = (const float*)d_in[6];
    const float* p1 = (const float*)d_in[7];
    const float* W2 = (const float*)d_in[8];
    const float* b2 = (const float*)d_in[9];
    const float* p2 = (const float*)d_in[10];
    const float* W3 = (const float*)d_in[11];
    const float* b3 = (const float*)d_in[12];
    const float* p3 = (const float*)d_in[13];
    const float* cw = (const float*)d_in[14];
    const float* cb = (const float*)d_in[15];
    float* out = (float*)d_out;
    char* w = (char*)d_ws;

    if (ws_size >= 84000000ull) {
        // ---- fast path ----
        // phase A buffers (prep/castproj): hb [0,2097152), pTb [2097152,4882432)
        // phase B buffers (sumexp/final): partials recycle the hb/pTb region
        u16*   hb   = (u16*)(w + 0);             // 1024x1024 bf16
        u16*   pTb  = (u16*)(w + 2097152);       // [1360][1024] bf16
        float* Ph   = (float*)(w + 0);           // [157][1024] f32 (recycles hb)
        float* Pt1  = (float*)(w + 643072);      // [40][1024]
        float* Pt2  = (float*)(w + 806912);      // [157][1024]
        float* Pt3  = (float*)(w + 1449984);     // [67][1024]   (ends 1724416 < 2097152)
        u16*   proj = (u16*)(w + 4882432);       // [1024][1360] bf16
        u16*   W0b  = (u16*)(w + 7667712);       // 19997x1024
        u16*   W1b  = (u16*)(w + 48621568);      // 20000x256
        u16*   W2b  = (u16*)(w + 58861568);      // 160000x64
        u16*   W3b  = (u16*)(w + 79341568);      // 67738x32 (zero-padded k16..31)
        int*   cnt  = (int*)(w + 83693184);      // 3 (+pad)
        int*   slot = (int*)(w + 83693200);      // 1024
        int*   rmap = (int*)(w + 83697296);      // 3x1024

        prep_small_k<<<1889, 256, 0, stream>>>(hidden, p0, p1, p2, p3, target,
                                               hb, pTb, cnt, slot, rmap);

        castproj_k<<<CP_GRID, 512, 0, stream>>>(hb, pTb, proj,
                                                W0, W1, W2, W3, W0b, W1b, W2b, W3b);

        sumexp_k<<<SE_GRID, 512, 0, stream>>>(proj, W0b, W1b, W2b, W3b,
                                              b0, b1, b2, b3,
                                              Ph, Pt1, Pt2, Pt3, rmap, cnt);

        final_k<<<256, 256, 0, stream>>>(proj, target, slot, cw, cb,
                                         W0, b0, W1, b1, W2, b2, W3, b3,
                                         Ph, Pt1, Pt2, Pt3, out);
    } else {
        // ---- round-1 verified fallback ----
        float* pT   = (float*)w;                          // [1360][1024] f32
        u16*   hb   = (u16*)(w + 5570560);                // [1024][1024] bf16
        u16*   proj = (u16*)(w + 7667712);                // [1024][1360] bf16
        float* rs   = (float*)(w + 10452992);
        float* cl   = (float*)(w + 10469376);
        float* tl   = (float*)(w + 10481664);
        dim3 tb(32, 8);

        hipMemsetAsync(rs, 0, 4 * 1024 * sizeof(float), stream);
        cast_bf16_k<<<512, 256, 0, stream>>>(hidden, hb, 131072);
        transpose_f_k<<<dim3(32, 32), tb, 0, stream>>>(p0, pT, 1024, 0);
        transpose_f_k<<<dim3(8, 32),  tb, 0, stream>>>(p1, pT, 256, 1024);
        transpose_f_k<<<dim3(2, 32),  tb, 0, stream>>>(p2, pT, 64, 1280);
        transpose_f_k<<<dim3(1, 32),  tb, 0, stream>>>(p3, pT, 16, 1344);

        gemm_tn_k<<<dim3(64, 6), 256, 0, stream>>>(hb, 1024, pT, 1024, nullptr,
                                                   1360, 1024, proj, LDP, nullptr);
        gemm_tn_k<<<dim3(64, 79), 256, 0, stream>>>(proj, LDP, W0, 1024, b0,
                                                    CUT1, 1024, nullptr, 0, rs);
        gemm_tn_k<<<dim3(64, 79), 256, 0, stream>>>(proj + 1024, LDP, W1, 256, b1,
                                                    20000, 256, nullptr, 0, rs + 1024);
        gemm_tn_k<<<dim3(64, 625), 256, 0, stream>>>(proj + 1280, LDP, W2, 64, b2,
                                                     160000, 64, nullptr, 0, rs + 2048);
        gemm_tn_k<<<dim3(64, 265), 256, 0, stream>>>(proj + 1344, LDP, W3, 16, b3,
                                                     67738, 16, nullptr, 0, rs + 3072);

        gather_k<<<256, 256, 0, stream>>>(proj, target, cw, cb,
                                          W0, b0, W1, b1, W2, b2, W3, b3, rs, cl, tl);
        finalize_full_k<<<4, 256, 0, stream>>>(target, rs, cl, tl, out);
    }
}